// Round 2
// 405.497 us; speedup vs baseline: 1.0244x; 1.0244x over previous
//
#include <hip/hip_runtime.h>
#include <math.h>

#define MUL0 64
#define MUL1 32
#define ROW_F 160          // floats per row of node_input / output
#define EPS2 1.0e-16f      // EPS^2
#define LOG2F_ 0.69314718055994531f
#define LP 65              // LDS transpose pad stride (65 % 32 == 1 -> 2-way max, free)
#define WPB 2              // waves per block
#define TPB (WPB * 64)

// native clang vector type: __builtin_nontemporal_store requires it
typedef float nfloat4 __attribute__((ext_vector_type(4)));

__device__ __forceinline__ void nt_store4(float* p, float x, float y, float z, float w)
{
    nfloat4 v = {x, y, z, w};
    __builtin_nontemporal_store(v, (nfloat4*)p);
}

// ---------------------------------------------------------------------------
// Kernel 1: combine the three weight matrices per path into one, with the
// normalization constants folded in.
//   ws[0    .. 2048) : W0c (32x64)  = C0 * W_tp_0e @ W_lin_0e @ W_sc_0e
//   ws[2048 .. 4096) : W1c (64x32)  = C1 * W_tp_1o @ W_lin_1o @ W_sc_1o
// ---------------------------------------------------------------------------
__global__ void combine_weights(const float* __restrict__ Wtp0,   // 32x64
                                const float* __restrict__ Wtp1,   // 64x32
                                const float* __restrict__ Wlin0,  // 64x64
                                const float* __restrict__ Wlin1,  // 32x32
                                const float* __restrict__ Wsc0,   // 64x64
                                const float* __restrict__ Wsc1,   // 32x32
                                float* __restrict__ ws)
{
    __shared__ float tmp0[32 * 64];
    __shared__ float tmp1[64 * 32];
    const int t = threadIdx.x;

    for (int i = t; i < 32 * 64; i += 256) {
        int u = i >> 6, w = i & 63;
        float acc = 0.f;
        for (int k = 0; k < 64; ++k) acc += Wtp0[u * 64 + k] * Wlin0[k * 64 + w];
        tmp0[i] = acc;
    }
    for (int i = t; i < 64 * 32; i += 256) {
        int u = i >> 5, w = i & 31;
        float acc = 0.f;
        for (int k = 0; k < 32; ++k) acc += Wtp1[u * 32 + k] * Wlin1[k * 32 + w];
        tmp1[i] = acc;
    }
    __syncthreads();

    const float C0 = 1.0f / (sqrtf(96.0f) * 64.0f);
    const float C1 = 1.0f / 256.0f;

    for (int i = t; i < 32 * 64; i += 256) {
        int u = i >> 6, w = i & 63;
        float acc = 0.f;
        for (int k = 0; k < 64; ++k) acc += tmp0[u * 64 + k] * Wsc0[k * 64 + w];
        ws[i] = C0 * acc;
    }
    for (int i = t; i < 64 * 32; i += 256) {
        int u = i >> 5, w = i & 31;
        float acc = 0.f;
        for (int k = 0; k < 32; ++k) acc += tmp1[u * 32 + k] * Wsc1[k * 32 + w];
        ws[2048 + i] = C1 * acc;
    }
}

// (softplus(n) - log 2) / n   for n > 0
__device__ __forceinline__ float ssp_over_n(float n)
{
    float sp = n + __logf(1.0f + __expf(-n)) - LOG2F_;
    return __fdividef(sp, n);
}

// Wave-local fence: buffer is wave-private and the DS pipe is in-order per
// wave, so we only need to stop the compiler from reordering LDS accesses.
__device__ __forceinline__ void wave_fence()
{
    __asm__ volatile("" ::: "memory");
    __builtin_amdgcn_wave_barrier();
}

// ---------------------------------------------------------------------------
// LDS transpose staging, split into issue (global->regs, batched, can be
// hoisted way ahead of use) and commit (regs->LDS->transposed regs).
// buf layout: [col][row], row-stride LP=65.
// ---------------------------------------------------------------------------
template<int W>
struct Stage {
    float4 v[W / 4];

    __device__ __forceinline__ void issue(const float* __restrict__ g,
                                          int lane, int rmax)
    {
        constexpr int NF4 = W / 4;
#pragma unroll
        for (int k = 0; k < NF4; ++k) {
            int id = k * 64 + lane;
            int r = id / NF4, gg = id % NF4;
            int rr = r <= rmax ? r : rmax;     // clamp (dup rows, benign)
            v[k] = *(const float4*)(g + rr * ROW_F + 4 * gg);
        }
    }

    __device__ __forceinline__ void commit(float* buf, int lane, float* dst)
    {
        constexpr int NF4 = W / 4;
        wave_fence();                          // WAR vs previous buf consumers
#pragma unroll
        for (int k = 0; k < NF4; ++k) {
            int id = k * 64 + lane;
            int r = id / NF4, gg = id % NF4;
            buf[(4 * gg + 0) * LP + r] = v[k].x;
            buf[(4 * gg + 1) * LP + r] = v[k].y;
            buf[(4 * gg + 2) * LP + r] = v[k].z;
            buf[(4 * gg + 3) * LP + r] = v[k].w;
        }
        wave_fence();
#pragma unroll
        for (int c = 0; c < W; ++c) dst[c] = buf[c * LP + lane];
    }
};

template<int W>
__device__ __forceinline__ void stage_out(float* __restrict__ g, float* buf,
                                          int lane, int rmax, const float* src)
{
    constexpr int NF4 = W / 4;
    wave_fence();                          // WAR vs previous buf reads
#pragma unroll
    for (int c = 0; c < W; ++c) buf[c * LP + lane] = src[c];
    wave_fence();
#pragma unroll
    for (int k = 0; k < NF4; ++k) {
        int id = k * 64 + lane;
        int r = id / NF4, gg = id % NF4;
        int rr = r <= rmax ? r : rmax;     // dup rows write identical data
        nt_store4(g + rr * ROW_F + 4 * gg,
                  buf[(4 * gg + 0) * LP + r],
                  buf[(4 * gg + 1) * LP + r],
                  buf[(4 * gg + 2) * LP + r],
                  buf[(4 * gg + 3) * LP + r]);
    }
}

// ---------------------------------------------------------------------------
// Kernel 2: 2 waves/block; each wave owns 64 rows, one row per lane.
// Weights are read straight from global: the addresses are wave-uniform so
// each read is a single broadcast request that stays L1-resident (16 KB
// total) -- this keeps the DS pipe free for the transposes and drops LDS to
// 25 KB/block -> 6 blocks/CU.
// ---------------------------------------------------------------------------
__global__ __launch_bounds__(TPB, 3)
void field_main(const float* __restrict__ in,     // N x 160
                const float* __restrict__ attr,   // N
                const float* __restrict__ field,  // N x 3
                const float* __restrict__ Wg,     // 4096 floats: W0c | W1c
                float* __restrict__ out,          // N x 160
                int nrows)
{
    __shared__ float tbuf[WPB][48 * LP];

    const int tid = threadIdx.x;
    const int wv = tid >> 6, lane = tid & 63;
    int r0 = (blockIdx.x * WPB + wv) * 64;
    if (r0 > nrows - 64) r0 = nrows - 64;          // overflow waves: dup work
    if (r0 < 0) r0 = 0;
    const int rmax = min(63, nrows - 1 - r0);
    const int rowe = r0 + min(lane, rmax);

    const float a  = attr[rowe];
    const float f0 = field[3 * rowe + 0];
    const float f1 = field[3 * rowe + 1];
    const float f2 = field[3 * rowe + 2];
    const float af0 = a * f0, af1 = a * f1, af2 = a * f2;

    const float* gin  = in  + (size_t)r0 * ROW_F;
    float*       gout = out + (size_t)r0 * ROW_F;
    float* buf = tbuf[wv];

    // ---- x0 (cols 0..64): both load batches in flight together ----
    float x0r[64];
    {
        Stage<32> A, B;
        A.issue(gin,      lane, rmax);
        B.issue(gin + 32, lane, rmax);
        A.commit(buf, lane, x0r);
        B.commit(buf, lane, x0r + 32);
    }

    // ---- issue x1 chunk 0 loads; their latency hides under the pw matmul ----
    Stage<48> C;
    C.issue(gin + 64, lane, rmax);

    // ---- pw[w] = a * sum_u x0[u] * W1c[u][w]  (uniform global weight reads) ----
    float pw[32];
#pragma unroll
    for (int w = 0; w < 32; ++w) pw[w] = 0.f;
#pragma unroll 4
    for (int u = 0; u < 64; ++u) {
        const float xu = x0r[u];
        const float4* wr = (const float4*)(Wg + 2048 + u * 32);
#pragma unroll
        for (int j = 0; j < 8; ++j) {
            float4 t = wr[j];
            pw[4 * j + 0] += xu * t.x;
            pw[4 * j + 1] += xu * t.y;
            pw[4 * j + 2] += xu * t.z;
            pw[4 * j + 3] += xu * t.w;
        }
    }
#pragma unroll
    for (int w = 0; w < 32; ++w) pw[w] *= a;

    float s1[32];
    Stage<48> D;

    // ---- x1 chunk 0 (u = 0..15): accumulate s1, emit gated o1 ----
    {
        float c[48];
        C.commit(buf, lane, c);
#pragma unroll
        for (int i = 0; i < 16; ++i) {
            const int u = i;
            const float m0 = c[3 * i], m1 = c[3 * i + 1], m2 = c[3 * i + 2];
            s1[u] = m0 * af0 + m1 * af1 + m2 * af2;
            const float p = pw[u];
            float q0 = m0 + p * f0;
            float q1 = m1 + p * f1;
            float q2 = m2 + p * f2;
            float n = sqrtf(q0 * q0 + q1 * q1 + q2 * q2 + EPS2);
            float t = ssp_over_n(n);
            c[3 * i] = q0 * t; c[3 * i + 1] = q1 * t; c[3 * i + 2] = q2 * t;
        }
        // stage_out chunk 0, hand-inlined so chunk-1 loads issue as soon as
        // c[] dies (after the LDS writes) -- overlaps D's HBM latency with
        // the transposed read-out + stores.
        wave_fence();
#pragma unroll
        for (int cc = 0; cc < 48; ++cc) buf[cc * LP + lane] = c[cc];
        D.issue(gin + 64 + 48, lane, rmax);
        wave_fence();
        float* g = gout + 64;
#pragma unroll
        for (int k = 0; k < 12; ++k) {
            int id = k * 64 + lane;
            int r = id / 12, gg = id % 12;
            int rr = r <= rmax ? r : rmax;
            nt_store4(g + rr * ROW_F + 4 * gg,
                      buf[(4 * gg + 0) * LP + r],
                      buf[(4 * gg + 1) * LP + r],
                      buf[(4 * gg + 2) * LP + r],
                      buf[(4 * gg + 3) * LP + r]);
        }
    }

    // ---- x1 chunk 1 (u = 16..31) ----
    {
        float c[48];
        D.commit(buf, lane, c);
#pragma unroll
        for (int i = 0; i < 16; ++i) {
            const int u = 16 + i;
            const float m0 = c[3 * i], m1 = c[3 * i + 1], m2 = c[3 * i + 2];
            s1[u] = m0 * af0 + m1 * af1 + m2 * af2;
            const float p = pw[u];
            float q0 = m0 + p * f0;
            float q1 = m1 + p * f1;
            float q2 = m2 + p * f2;
            float n = sqrtf(q0 * q0 + q1 * q1 + q2 * q2 + EPS2);
            float t = ssp_over_n(n);
            c[3 * i] = q0 * t; c[3 * i + 1] = q1 * t; c[3 * i + 2] = q2 * t;
        }
        stage_out<48>(gout + 64 + 48, buf, lane, rmax, c);
    }

    // ---- z0 = s1 @ W0c (uniform global weight reads); o0 = gate(x0 + z0) ----
#pragma unroll
    for (int wc = 0; wc < 2; ++wc) {
        float acc[32];
#pragma unroll
        for (int j = 0; j < 32; ++j) acc[j] = 0.f;
#pragma unroll 4
        for (int u = 0; u < 32; ++u) {
            const float su = s1[u];
            const float4* wr = (const float4*)(Wg + u * 64 + 32 * wc);
#pragma unroll
            for (int j = 0; j < 8; ++j) {
                float4 t = wr[j];
                acc[4 * j + 0] += su * t.x;
                acc[4 * j + 1] += su * t.y;
                acc[4 * j + 2] += su * t.z;
                acc[4 * j + 3] += su * t.w;
            }
        }
#pragma unroll
        for (int j = 0; j < 32; ++j) {
            float r = x0r[32 * wc + j] + acc[j];
            float n = sqrtf(r * r + EPS2);
            acc[j] = r * ssp_over_n(n);
        }
        stage_out<32>(gout + 32 * wc, buf, lane, rmax, acc);
    }
}

extern "C" void kernel_launch(void* const* d_in, const int* in_sizes, int n_in,
                              void* d_out, int out_size, void* d_ws, size_t ws_size,
                              hipStream_t stream)
{
    const float* node_input = (const float*)d_in[0];
    const float* node_attr  = (const float*)d_in[1];
    const float* field      = (const float*)d_in[2];
    const float* Wtp0       = (const float*)d_in[3];
    const float* Wtp1       = (const float*)d_in[4];
    const float* Wlin0      = (const float*)d_in[5];
    const float* Wlin1      = (const float*)d_in[6];
    const float* Wsc0       = (const float*)d_in[7];
    const float* Wsc1       = (const float*)d_in[8];
    float* out = (float*)d_out;
    float* ws  = (float*)d_ws;

    const int nrows = in_sizes[0] / ROW_F;   // 200000

    hipLaunchKernelGGL(combine_weights, dim3(1), dim3(256), 0, stream,
                       Wtp0, Wtp1, Wlin0, Wlin1, Wsc0, Wsc1, ws);

    const int nwaves = (nrows + 63) / 64;
    const int nb = (nwaves + WPB - 1) / WPB;
    hipLaunchKernelGGL(field_main, dim3(nb), dim3(TPB), 0, stream,
                       node_input, node_attr, field, ws, out, nrows);
}

// Round 3
// 386.704 us; speedup vs baseline: 1.0742x; 1.0486x over previous
//
#include <hip/hip_runtime.h>
#include <math.h>

#define MUL0 64
#define MUL1 32
#define ROW_F 160          // floats per row of node_input / output
#define EPS2 1.0e-16f      // EPS^2
#define LOG2F_ 0.69314718055994531f
#define LP 65              // LDS transpose pad stride (65 % 32 == 1 -> 2-way max, free)
#define WPB 2              // waves per block
#define TPB (WPB * 64)

// ---------------------------------------------------------------------------
// Kernel 1: combine the three weight matrices per path into one, with the
// normalization constants folded in.
//   ws[0    .. 2048) : W0c (32x64)  = C0 * W_tp_0e @ W_lin_0e @ W_sc_0e
//   ws[2048 .. 4096) : W1c (64x32)  = C1 * W_tp_1o @ W_lin_1o @ W_sc_1o
// All matrices staged to LDS first (coalesced float4); both phases run as
// float4-wide LDS matmuls across 1024 threads -> no global-latency chains.
// ---------------------------------------------------------------------------
#define OT0   0            // Wtp0  32x64  (2048)
#define OL0   2048         // Wlin0 64x64  (4096)
#define OS0   6144         // Wsc0  64x64  (4096)
#define OT1   10240        // Wtp1  64x32  (2048)
#define OL1   12288        // Wlin1 32x32  (1024)
#define OS1   13312        // Wsc1  32x32  (1024)
#define OM0   14336        // tmp0  32x64  (2048)
#define OM1   16384        // tmp1  64x32  (2048)
#define CW_LDS 18432       // floats

__global__ __launch_bounds__(1024)
void combine_weights(const float* __restrict__ Wtp0,   // 32x64
                     const float* __restrict__ Wtp1,   // 64x32
                     const float* __restrict__ Wlin0,  // 64x64
                     const float* __restrict__ Wlin1,  // 32x32
                     const float* __restrict__ Wsc0,   // 64x64
                     const float* __restrict__ Wsc1,   // 32x32
                     float* __restrict__ ws)
{
    __shared__ float L[CW_LDS];
    const int t = threadIdx.x;

    // ---- coalesced float4 staging of all six matrices ----
    {
        const float* srcs[6] = {Wtp0, Wlin0, Wsc0, Wtp1, Wlin1, Wsc1};
        const int    offs[6] = {OT0, OL0, OS0, OT1, OL1, OS1};
        const int    n4s[6]  = {512, 1024, 1024, 512, 256, 256};
#pragma unroll
        for (int m = 0; m < 6; ++m) {
            const float4* s = (const float4*)srcs[m];
            float4* d = (float4*)(L + offs[m]);
            for (int i = t; i < n4s[m]; i += 1024) d[i] = s[i];
        }
    }
    __syncthreads();

    // ---- phase 1: tmp0 = Wtp0 @ Wlin0 (32x64), tmp1 = Wtp1 @ Wlin1 (64x32)
    //      one float4 of output per thread; 'b' operand reads broadcast ----
    if (t < 512) {
        const int u = t >> 4, q = t & 15;          // tmp0: 32 rows x 16 quads
        float4 acc = {0.f, 0.f, 0.f, 0.f};
#pragma unroll 8
        for (int k = 0; k < 64; ++k) {
            const float a = L[OT0 + u * 64 + k];
            const float4 b = ((const float4*)(L + OL0))[k * 16 + q];
            acc.x += a * b.x; acc.y += a * b.y; acc.z += a * b.z; acc.w += a * b.w;
        }
        ((float4*)(L + OM0))[u * 16 + q] = acc;
    } else {
        const int t2 = t - 512;
        const int u = t2 >> 3, q = t2 & 7;         // tmp1: 64 rows x 8 quads
        float4 acc = {0.f, 0.f, 0.f, 0.f};
#pragma unroll 8
        for (int k = 0; k < 32; ++k) {
            const float a = L[OT1 + u * 32 + k];
            const float4 b = ((const float4*)(L + OL1))[k * 8 + q];
            acc.x += a * b.x; acc.y += a * b.y; acc.z += a * b.z; acc.w += a * b.w;
        }
        ((float4*)(L + OM1))[u * 8 + q] = acc;
    }
    __syncthreads();

    // ---- phase 2: ws0 = C0 * tmp0 @ Wsc0, ws1 = C1 * tmp1 @ Wsc1 ----
    const float C0 = 1.0f / (sqrtf(96.0f) * 64.0f);
    const float C1 = 1.0f / 256.0f;
    if (t < 512) {
        const int u = t >> 4, q = t & 15;
        float4 acc = {0.f, 0.f, 0.f, 0.f};
#pragma unroll 8
        for (int k = 0; k < 64; ++k) {
            const float a = L[OM0 + u * 64 + k];
            const float4 b = ((const float4*)(L + OS0))[k * 16 + q];
            acc.x += a * b.x; acc.y += a * b.y; acc.z += a * b.z; acc.w += a * b.w;
        }
        acc.x *= C0; acc.y *= C0; acc.z *= C0; acc.w *= C0;
        ((float4*)ws)[u * 16 + q] = acc;
    } else {
        const int t2 = t - 512;
        const int u = t2 >> 3, q = t2 & 7;
        float4 acc = {0.f, 0.f, 0.f, 0.f};
#pragma unroll 8
        for (int k = 0; k < 32; ++k) {
            const float a = L[OM1 + u * 32 + k];
            const float4 b = ((const float4*)(L + OS1))[k * 8 + q];
            acc.x += a * b.x; acc.y += a * b.y; acc.z += a * b.z; acc.w += a * b.w;
        }
        acc.x *= C1; acc.y *= C1; acc.z *= C1; acc.w *= C1;
        ((float4*)(ws + 2048))[u * 8 + q] = acc;
    }
}

// (softplus(n) - log 2) / n   for n > 0
__device__ __forceinline__ float ssp_over_n(float n)
{
    float sp = n + __logf(1.0f + __expf(-n)) - LOG2F_;
    return __fdividef(sp, n);
}

// Wave-local fence: buffer is wave-private and the DS pipe is in-order per
// wave, so we only need to stop the compiler from reordering LDS accesses.
__device__ __forceinline__ void wave_fence()
{
    __asm__ volatile("" ::: "memory");
    __builtin_amdgcn_wave_barrier();
}

// ---------------------------------------------------------------------------
// LDS transpose staging, split into issue (global->regs, batched, can be
// hoisted way ahead of use) and commit (regs->LDS->transposed regs).
// buf layout: [col][row], row-stride LP=65.
// ---------------------------------------------------------------------------
template<int W>
struct Stage {
    float4 v[W / 4];

    __device__ __forceinline__ void issue(const float* __restrict__ g,
                                          int lane, int rmax)
    {
        constexpr int NF4 = W / 4;
#pragma unroll
        for (int k = 0; k < NF4; ++k) {
            int id = k * 64 + lane;
            int r = id / NF4, gg = id % NF4;
            int rr = r <= rmax ? r : rmax;     // clamp (dup rows, benign)
            v[k] = *(const float4*)(g + rr * ROW_F + 4 * gg);
        }
    }

    __device__ __forceinline__ void commit(float* buf, int lane, float* dst)
    {
        constexpr int NF4 = W / 4;
        wave_fence();                          // WAR vs previous buf consumers
#pragma unroll
        for (int k = 0; k < NF4; ++k) {
            int id = k * 64 + lane;
            int r = id / NF4, gg = id % NF4;
            buf[(4 * gg + 0) * LP + r] = v[k].x;
            buf[(4 * gg + 1) * LP + r] = v[k].y;
            buf[(4 * gg + 2) * LP + r] = v[k].z;
            buf[(4 * gg + 3) * LP + r] = v[k].w;
        }
        wave_fence();
#pragma unroll
        for (int c = 0; c < W; ++c) dst[c] = buf[c * LP + lane];
    }
};

template<int W>
__device__ __forceinline__ void stage_out(float* __restrict__ g, float* buf,
                                          int lane, int rmax, const float* src)
{
    constexpr int NF4 = W / 4;
    wave_fence();                          // WAR vs previous buf reads
#pragma unroll
    for (int c = 0; c < W; ++c) buf[c * LP + lane] = src[c];
    wave_fence();
#pragma unroll
    for (int k = 0; k < NF4; ++k) {
        int id = k * 64 + lane;
        int r = id / NF4, gg = id % NF4;
        int rr = r <= rmax ? r : rmax;     // dup rows write identical data
        float4 v;
        v.x = buf[(4 * gg + 0) * LP + r];
        v.y = buf[(4 * gg + 1) * LP + r];
        v.z = buf[(4 * gg + 2) * LP + r];
        v.w = buf[(4 * gg + 3) * LP + r];
        *(float4*)(g + rr * ROW_F + 4 * gg) = v;
    }
}

// ---------------------------------------------------------------------------
// Kernel 2: 2 waves/block; each wave owns 64 rows, one row per lane.
// Weights are read straight from global: the addresses are wave-uniform so
// each read is a single broadcast request that stays L1-resident (16 KB
// total) -- this keeps the DS pipe free for the transposes and drops LDS to
// 25 KB/block -> 6 blocks/CU.
// ---------------------------------------------------------------------------
__global__ __launch_bounds__(TPB, 3)
void field_main(const float* __restrict__ in,     // N x 160
                const float* __restrict__ attr,   // N
                const float* __restrict__ field,  // N x 3
                const float* __restrict__ Wg,     // 4096 floats: W0c | W1c
                float* __restrict__ out,          // N x 160
                int nrows)
{
    __shared__ float tbuf[WPB][48 * LP];

    const int tid = threadIdx.x;
    const int wv = tid >> 6, lane = tid & 63;
    int r0 = (blockIdx.x * WPB + wv) * 64;
    if (r0 > nrows - 64) r0 = nrows - 64;          // overflow waves: dup work
    if (r0 < 0) r0 = 0;
    const int rmax = min(63, nrows - 1 - r0);
    const int rowe = r0 + min(lane, rmax);

    const float a  = attr[rowe];
    const float f0 = field[3 * rowe + 0];
    const float f1 = field[3 * rowe + 1];
    const float f2 = field[3 * rowe + 2];
    const float af0 = a * f0, af1 = a * f1, af2 = a * f2;

    const float* gin  = in  + (size_t)r0 * ROW_F;
    float*       gout = out + (size_t)r0 * ROW_F;
    float* buf = tbuf[wv];

    // ---- x0 (cols 0..64): both load batches in flight together ----
    float x0r[64];
    {
        Stage<32> A, B;
        A.issue(gin,      lane, rmax);
        B.issue(gin + 32, lane, rmax);
        A.commit(buf, lane, x0r);
        B.commit(buf, lane, x0r + 32);
    }

    // ---- issue x1 chunk 0 loads; their latency hides under the pw matmul ----
    Stage<48> C;
    C.issue(gin + 64, lane, rmax);

    // ---- pw[w] = a * sum_u x0[u] * W1c[u][w]  (uniform global weight reads) ----
    float pw[32];
#pragma unroll
    for (int w = 0; w < 32; ++w) pw[w] = 0.f;
#pragma unroll 4
    for (int u = 0; u < 64; ++u) {
        const float xu = x0r[u];
        const float4* wr = (const float4*)(Wg + 2048 + u * 32);
#pragma unroll
        for (int j = 0; j < 8; ++j) {
            float4 t = wr[j];
            pw[4 * j + 0] += xu * t.x;
            pw[4 * j + 1] += xu * t.y;
            pw[4 * j + 2] += xu * t.z;
            pw[4 * j + 3] += xu * t.w;
        }
    }
#pragma unroll
    for (int w = 0; w < 32; ++w) pw[w] *= a;

    float s1[32];
    Stage<48> D;

    // ---- x1 chunk 0 (u = 0..15): accumulate s1, emit gated o1 ----
    {
        float c[48];
        C.commit(buf, lane, c);
#pragma unroll
        for (int i = 0; i < 16; ++i) {
            const int u = i;
            const float m0 = c[3 * i], m1 = c[3 * i + 1], m2 = c[3 * i + 2];
            s1[u] = m0 * af0 + m1 * af1 + m2 * af2;
            const float p = pw[u];
            float q0 = m0 + p * f0;
            float q1 = m1 + p * f1;
            float q2 = m2 + p * f2;
            float n = sqrtf(q0 * q0 + q1 * q1 + q2 * q2 + EPS2);
            float t = ssp_over_n(n);
            c[3 * i] = q0 * t; c[3 * i + 1] = q1 * t; c[3 * i + 2] = q2 * t;
        }
        // stage_out chunk 0, hand-inlined so chunk-1 loads issue as soon as
        // c[] dies (after the LDS writes) -- overlaps D's HBM latency with
        // the transposed read-out + stores.
        wave_fence();
#pragma unroll
        for (int cc = 0; cc < 48; ++cc) buf[cc * LP + lane] = c[cc];
        D.issue(gin + 64 + 48, lane, rmax);
        wave_fence();
        float* g = gout + 64;
#pragma unroll
        for (int k = 0; k < 12; ++k) {
            int id = k * 64 + lane;
            int r = id / 12, gg = id % 12;
            int rr = r <= rmax ? r : rmax;
            float4 v;
            v.x = buf[(4 * gg + 0) * LP + r];
            v.y = buf[(4 * gg + 1) * LP + r];
            v.z = buf[(4 * gg + 2) * LP + r];
            v.w = buf[(4 * gg + 3) * LP + r];
            *(float4*)(g + rr * ROW_F + 4 * gg) = v;
        }
    }

    // ---- x1 chunk 1 (u = 16..31) ----
    {
        float c[48];
        D.commit(buf, lane, c);
#pragma unroll
        for (int i = 0; i < 16; ++i) {
            const int u = 16 + i;
            const float m0 = c[3 * i], m1 = c[3 * i + 1], m2 = c[3 * i + 2];
            s1[u] = m0 * af0 + m1 * af1 + m2 * af2;
            const float p = pw[u];
            float q0 = m0 + p * f0;
            float q1 = m1 + p * f1;
            float q2 = m2 + p * f2;
            float n = sqrtf(q0 * q0 + q1 * q1 + q2 * q2 + EPS2);
            float t = ssp_over_n(n);
            c[3 * i] = q0 * t; c[3 * i + 1] = q1 * t; c[3 * i + 2] = q2 * t;
        }
        stage_out<48>(gout + 64 + 48, buf, lane, rmax, c);
    }

    // ---- z0 = s1 @ W0c (uniform global weight reads); o0 = gate(x0 + z0) ----
#pragma unroll
    for (int wc = 0; wc < 2; ++wc) {
        float acc[32];
#pragma unroll
        for (int j = 0; j < 32; ++j) acc[j] = 0.f;
#pragma unroll 4
        for (int u = 0; u < 32; ++u) {
            const float su = s1[u];
            const float4* wr = (const float4*)(Wg + u * 64 + 32 * wc);
#pragma unroll
            for (int j = 0; j < 8; ++j) {
                float4 t = wr[j];
                acc[4 * j + 0] += su * t.x;
                acc[4 * j + 1] += su * t.y;
                acc[4 * j + 2] += su * t.z;
                acc[4 * j + 3] += su * t.w;
            }
        }
#pragma unroll
        for (int j = 0; j < 32; ++j) {
            float r = x0r[32 * wc + j] + acc[j];
            float n = sqrtf(r * r + EPS2);
            acc[j] = r * ssp_over_n(n);
        }
        stage_out<32>(gout + 32 * wc, buf, lane, rmax, acc);
    }
}

extern "C" void kernel_launch(void* const* d_in, const int* in_sizes, int n_in,
                              void* d_out, int out_size, void* d_ws, size_t ws_size,
                              hipStream_t stream)
{
    const float* node_input = (const float*)d_in[0];
    const float* node_attr  = (const float*)d_in[1];
    const float* field      = (const float*)d_in[2];
    const float* Wtp0       = (const float*)d_in[3];
    const float* Wtp1       = (const float*)d_in[4];
    const float* Wlin0      = (const float*)d_in[5];
    const float* Wlin1      = (const float*)d_in[6];
    const float* Wsc0       = (const float*)d_in[7];
    const float* Wsc1       = (const float*)d_in[8];
    float* out = (float*)d_out;
    float* ws  = (float*)d_ws;

    const int nrows = in_sizes[0] / ROW_F;   // 200000

    hipLaunchKernelGGL(combine_weights, dim3(1), dim3(1024), 0, stream,
                       Wtp0, Wtp1, Wlin0, Wlin1, Wsc0, Wsc1, ws);

    const int nwaves = (nrows + 63) / 64;
    const int nb = (nwaves + WPB - 1) / WPB;
    hipLaunchKernelGGL(field_main, dim3(nb), dim3(TPB), 0, stream,
                       node_input, node_attr, field, ws, out, nrows);
}